// Round 4
// baseline (365.753 us; speedup 1.0000x reference)
//
#include <hip/hip_runtime.h>
#include <hip/hip_bf16.h>
#include <math.h>

#define N_NODES 4096
#define F_IN0   512
#define HEADS   4
#define O_DIM   256
#define HO      1024   // HEADS*O_DIM
#define LRELU_A 0.2f
#define MAXE    192

typedef __bf16 bf16_t;
typedef bf16_t bf16x8 __attribute__((ext_vector_type(8)));
typedef float f32x4 __attribute__((ext_vector_type(4)));

__device__ __forceinline__ unsigned short f2b(float f) {
    __hip_bfloat16 t = __float2bfloat16(f);
    return __builtin_bit_cast(unsigned short, t);
}
__device__ __forceinline__ float b2f(unsigned short u) {
    unsigned int v = ((unsigned int)u) << 16;
    return __builtin_bit_cast(float, v);
}

#define GLOAD_LDS(g, l) \
    __builtin_amdgcn_global_load_lds((const __attribute__((address_space(1))) unsigned int*)(g), \
                                     (__attribute__((address_space(3))) unsigned int*)(l), 16, 0, 0)

// ---------------- fp32 -> bf16 bulk convert
__global__ __launch_bounds__(256) void f2bf_k(const float* __restrict__ src,
                                              unsigned short* __restrict__ dst, int n4) {
    int i = blockIdx.x * blockDim.x + threadIdx.x;
    if (i < n4) {
        float4 v = ((const float4*)src)[i];
        ushort4 o;
        o.x = f2b(v.x); o.y = f2b(v.y); o.z = f2b(v.z); o.w = f2b(v.w);
        ((ushort4*)dst)[i] = o;
    }
}

// ---------------- W [H,K,O] fp32 -> Wt [H,O,K] bf16
__global__ __launch_bounds__(256) void transpose_bf16(const float* __restrict__ W,
                                                      unsigned short* __restrict__ Wt,
                                                      int K, int O) {
    __shared__ float t[32][33];
    const float* Wh = W + (size_t)blockIdx.z * K * O;
    unsigned short* Wth = Wt + (size_t)blockIdx.z * K * O;
    const int k0 = blockIdx.x * 32, o0 = blockIdx.y * 32;
    const int tx = threadIdx.x, ty = threadIdx.y;  // 32 x 8
    for (int r = ty; r < 32; r += 8) t[r][tx] = Wh[(size_t)(k0 + r) * O + o0 + tx];
    __syncthreads();
    for (int r = ty; r < 32; r += 8)
        Wth[(size_t)(o0 + r) * K + k0 + tx] = f2b(t[tx][r]);
}

// ---------------- edge list build
__global__ __launch_bounds__(256) void edges_k(const float* __restrict__ adj,
                                               const float* __restrict__ Mm,
                                               int* __restrict__ ecnt,
                                               int* __restrict__ eidx,
                                               float* __restrict__ eMv) {
    const int n = blockIdx.x;
    const int tid = threadIdx.x;
    __shared__ int cnt;
    if (tid == 0) cnt = 0;
    __syncthreads();
    const float* adjr = adj + (size_t)n * N_NODES;
    const float* Mr   = Mm  + (size_t)n * N_NODES;
    for (int m0 = tid * 4; m0 < N_NODES; m0 += 1024) {
        const float4 a4 = *(const float4*)&adjr[m0];
        const float av[4] = {a4.x, a4.y, a4.z, a4.w};
#pragma unroll
        for (int q = 0; q < 4; ++q) {
            if (av[q] > 0.f) {
                int m = m0 + q;
                int k = atomicAdd(&cnt, 1);
                eidx[(size_t)n * MAXE + k] = m;
                eMv[(size_t)n * MAXE + k]  = Mr[m];
            }
        }
    }
    __syncthreads();
    if (tid == 0) ecnt[n] = cnt;
}

// ---------------- MFMA NT GEMM (LDS-staged; used for the two layer GEMMs)
__global__ __launch_bounds__(256) void mfma_nt(const bf16_t* __restrict__ A,
                                               const bf16_t* __restrict__ B,
                                               unsigned short* __restrict__ Cv,
                                               int K, int ldc,
                                               unsigned long long bStride,
                                               unsigned long long cStride) {
    B += blockIdx.z * bStride;
    const size_t zoff = (size_t)blockIdx.z * cStride;
    __shared__ bf16_t sA[128 * 32];
    __shared__ bf16_t sB[128 * 32];
    const int tid  = threadIdx.x;
    const int lane = tid & 63;
    const int wave = tid >> 6;
    const int wr = (wave >> 1) * 64;
    const int wc = (wave & 1) * 64;
    const int rowBase = blockIdx.x * 128;
    const int colBase = blockIdx.y * 128;
    const int l15  = lane & 15;
    const int quad = lane >> 4;

    const int sm = tid & 127;
    const int sc = tid >> 7;
    const bf16_t* aRow = A + (size_t)(rowBase + sm) * K + sc * 8;
    const bf16_t* bRow = B + (size_t)(colBase + sm) * K + sc * 8;
    bf16_t* sA0 = &sA[(tid & ~63) * 8];
    bf16_t* sA1 = &sA[(256 + (tid & ~63)) * 8];
    bf16_t* sB0 = &sB[(tid & ~63) * 8];
    bf16_t* sB1 = &sB[(256 + (tid & ~63)) * 8];

    f32x4 acc[4][4] = {};

    for (int k0 = 0; k0 < K; k0 += 32) {
        GLOAD_LDS(aRow + k0,      sA0);
        GLOAD_LDS(aRow + k0 + 16, sA1);
        GLOAD_LDS(bRow + k0,      sB0);
        GLOAD_LDS(bRow + k0 + 16, sB1);
        __syncthreads();
        bf16x8 af[4], bfr[4];
#pragma unroll
        for (int i = 0; i < 4; ++i) {
            af[i]  = *(bf16x8*)&sA[(quad * 128 + wr + i * 16 + l15) * 8];
            bfr[i] = *(bf16x8*)&sB[(quad * 128 + wc + i * 16 + l15) * 8];
        }
#pragma unroll
        for (int i = 0; i < 4; ++i)
#pragma unroll
            for (int j = 0; j < 4; ++j)
                acc[i][j] = __builtin_amdgcn_mfma_f32_16x16x32_bf16(af[i], bfr[j], acc[i][j], 0, 0, 0);
        __syncthreads();
    }

    const int orow = rowBase + wr + quad * 4;
    const int ocol = colBase + wc + l15;
#pragma unroll
    for (int i = 0; i < 4; ++i)
#pragma unroll
        for (int j = 0; j < 4; ++j)
#pragma unroll
            for (int r = 0; r < 4; ++r)
                Cv[zoff + (size_t)(orow + i * 16 + r) * ldc + ocol + j * 16] = f2b(acc[i][j][r]);
}

// ---------------- decode: out = sigmoid(Z Z^T), Z bf16 [N,256] (L2-resident)
// Direct global fragment loads, no LDS, no barriers. One wave = 64x64 tile.
__global__ __launch_bounds__(256) void decode_k(const bf16_t* __restrict__ Z,
                                                float* __restrict__ out) {
    const int tid  = threadIdx.x;
    const int lane = tid & 63;
    const int wave = tid >> 6;
    const int rowBase = blockIdx.x * 128 + (wave >> 1) * 64;
    const int colBase = blockIdx.y * 128 + (wave & 1) * 64;
    const int l15  = lane & 15;
    const int quad = lane >> 4;
    const bf16_t* aBase = Z + (size_t)(rowBase + l15) * O_DIM + quad * 8;
    const bf16_t* bBase = Z + (size_t)(colBase + l15) * O_DIM + quad * 8;

    f32x4 acc[4][4] = {};
#pragma unroll
    for (int kc = 0; kc < 8; ++kc) {
        bf16x8 a[4], b[4];
#pragma unroll
        for (int i = 0; i < 4; ++i) {
            a[i] = *(const bf16x8*)(aBase + (size_t)i * 16 * O_DIM + kc * 32);
            b[i] = *(const bf16x8*)(bBase + (size_t)i * 16 * O_DIM + kc * 32);
        }
#pragma unroll
        for (int i = 0; i < 4; ++i)
#pragma unroll
            for (int j = 0; j < 4; ++j)
                acc[i][j] = __builtin_amdgcn_mfma_f32_16x16x32_bf16(a[i], b[j], acc[i][j], 0, 0, 0);
    }

    const int orow = rowBase + quad * 4;
    const int ocol = colBase + l15;
#pragma unroll
    for (int i = 0; i < 4; ++i)
#pragma unroll
        for (int j = 0; j < 4; ++j)
#pragma unroll
            for (int r = 0; r < 4; ++r) {
                float v = acc[i][j][r];
                out[(size_t)(orow + i * 16 + r) * N_NODES + ocol + j * 16] =
                    1.f / (1.f + expf(-v));
            }
}

// ---------------- scores from bf16 h[n][h*256+o]
__global__ __launch_bounds__(256) void scores_k(const unsigned short* __restrict__ hb,
                                                const float* __restrict__ a_s,
                                                const float* __restrict__ a_n,
                                                float* __restrict__ s_self4,
                                                float* __restrict__ s_neigh4) {
    const int n = blockIdx.x;
    const int head = threadIdx.x >> 6;
    const int lane = threadIdx.x & 63;
    const ushort4 hv = *(const ushort4*)&hb[(size_t)n * HO + head * O_DIM + lane * 4];
    const float4 av = *(const float4*)&a_s[head * O_DIM + lane * 4];
    const float4 nv = *(const float4*)&a_n[head * O_DIM + lane * 4];
    float h0 = b2f(hv.x), h1 = b2f(hv.y), h2 = b2f(hv.z), h3 = b2f(hv.w);
    float ps = h0 * av.x + h1 * av.y + h2 * av.z + h3 * av.w;
    float pn = h0 * nv.x + h1 * nv.y + h2 * nv.z + h3 * nv.w;
    for (int off = 32; off; off >>= 1) {
        ps += __shfl_down(ps, off, 64);
        pn += __shfl_down(pn, off, 64);
    }
    if (lane == 0) {
        s_self4[n * HEADS + head]  = ps;
        s_neigh4[n * HEADS + head] = pn;
    }
}

// ---------------- sparse attention from edge list; h bf16 n-major
__global__ __launch_bounds__(256) void attn_k(const unsigned short* __restrict__ hb,
                                              const int* __restrict__ ecnt,
                                              const int* __restrict__ eidx,
                                              const float* __restrict__ eMv,
                                              const float* __restrict__ s_self4,
                                              const float* __restrict__ s_neigh4,
                                              unsigned short* __restrict__ out0,
                                              float* __restrict__ out1, int layer) {
    const int n = blockIdx.x;
    const int tid = threadIdx.x;
    __shared__ int midx[MAXE];
    __shared__ float ev[MAXE][HEADS];
    __shared__ float isum[HEADS];
    __shared__ float red[HO];
    const int c = ecnt[n];
    if (tid < c) {
        const int m = eidx[(size_t)n * MAXE + tid];
        const float Mv = eMv[(size_t)n * MAXE + tid];
        midx[tid] = m;
        const float4 ss = *(const float4*)&s_self4[n * HEADS];
        const float4 sn = *(const float4*)&s_neigh4[m * HEADS];
        float e0 = (ss.x + sn.x) * Mv, e1 = (ss.y + sn.y) * Mv;
        float e2 = (ss.z + sn.z) * Mv, e3 = (ss.w + sn.w) * Mv;
        ev[tid][0] = e0 > 0.f ? e0 : LRELU_A * e0;
        ev[tid][1] = e1 > 0.f ? e1 : LRELU_A * e1;
        ev[tid][2] = e2 > 0.f ? e2 : LRELU_A * e2;
        ev[tid][3] = e3 > 0.f ? e3 : LRELU_A * e3;
    }
    __syncthreads();
    if (tid < HEADS) {
        float mx = -1e30f;
        for (int k = 0; k < c; ++k) mx = fmaxf(mx, ev[k][tid]);
        float s = 0.f;
        for (int k = 0; k < c; ++k) {
            float p = expf(ev[k][tid] - mx);
            ev[k][tid] = p;
            s += p;
        }
        isum[tid] = 1.f / s;
    }
    __syncthreads();
    for (int i = tid; i < c * HEADS; i += 256) {
        int k = i >> 2, h = i & 3;
        ev[k][h] *= isum[h];
    }
    __syncthreads();
    const int head = tid >> 6;
    float a0 = 0.f, a1 = 0.f, a2 = 0.f, a3 = 0.f;
#pragma unroll 4
    for (int k = 0; k < c; ++k) {
        const int m = midx[k];
        const float w = ev[k][head];
        const ushort4 hv = *(const ushort4*)&hb[(size_t)m * HO + tid * 4];
        a0 += w * b2f(hv.x); a1 += w * b2f(hv.y);
        a2 += w * b2f(hv.z); a3 += w * b2f(hv.w);
    }
    if (layer == 0) {
        a0 = a0 > 0.f ? a0 : expm1f(a0);
        a1 = a1 > 0.f ? a1 : expm1f(a1);
        a2 = a2 > 0.f ? a2 : expm1f(a2);
        a3 = a3 > 0.f ? a3 : expm1f(a3);
        ushort4 o;
        o.x = f2b(a0); o.y = f2b(a1); o.z = f2b(a2); o.w = f2b(a3);
        *(ushort4*)&out0[(size_t)n * HO + tid * 4] = o;
    } else {
        red[tid * 4 + 0] = a0; red[tid * 4 + 1] = a1;
        red[tid * 4 + 2] = a2; red[tid * 4 + 3] = a3;
        __syncthreads();
        const int o = tid;
        out1[(size_t)n * O_DIM + o] =
            0.25f * (red[o] + red[O_DIM + o] + red[2 * O_DIM + o] + red[3 * O_DIM + o]);
    }
}

// ---------------- row L2 normalize + bf16 copy
__global__ __launch_bounds__(256) void norm_k(float* __restrict__ z,
                                              unsigned short* __restrict__ zb) {
    const int n = blockIdx.x;
    const int tid = threadIdx.x;
    float v = z[(size_t)n * O_DIM + tid];
    float p = v * v;
    for (int off = 32; off; off >>= 1) p += __shfl_down(p, off, 64);
    __shared__ float wsum[4];
    if ((tid & 63) == 0) wsum[tid >> 6] = p;
    __syncthreads();
    float ssq = wsum[0] + wsum[1] + wsum[2] + wsum[3];
    float denom = fmaxf(sqrtf(ssq), 1e-12f);
    float zn = v / denom;
    z[(size_t)n * O_DIM + tid] = zn;
    zb[(size_t)n * O_DIM + tid] = f2b(zn);
}

extern "C" void kernel_launch(void* const* d_in, const int* in_sizes, int n_in,
                              void* d_out, int out_size, void* d_ws, size_t ws_size,
                              hipStream_t stream) {
    const float* x   = (const float*)d_in[0];
    const float* adj = (const float*)d_in[1];
    const float* Mm  = (const float*)d_in[2];
    const float* W0  = (const float*)d_in[3];
    const float* as0 = (const float*)d_in[4];
    const float* an0 = (const float*)d_in[5];
    const float* W1  = (const float*)d_in[6];
    const float* as1 = (const float*)d_in[7];
    const float* an1 = (const float*)d_in[8];
    float* out = (float*)d_out;

    unsigned short* hb    = (unsigned short*)d_ws;        // [N][HO] bf16, 8 MB
    unsigned short* hin1b = hb + (size_t)N_NODES * HO;    // [N][HO] bf16, 8 MB
    unsigned short* xb    = hin1b + (size_t)N_NODES * HO; // [N][F] bf16, 4 MB
    unsigned short* wt0   = xb + (size_t)N_NODES * F_IN0; // 1 MB
    unsigned short* wt1   = wt0 + HEADS * O_DIM * F_IN0;  // 2 MB
    unsigned short* zb    = wt1 + HEADS * O_DIM * HO;     // [N][O] bf16, 2 MB
    float* s_self4  = (float*)(zb + (size_t)N_NODES * O_DIM);
    float* s_neigh4 = s_self4 + N_NODES * HEADS;
    int*   eidx = (int*)(s_neigh4 + N_NODES * HEADS);
    float* eMv  = (float*)(eidx + (size_t)N_NODES * MAXE);
    int*   ecnt = (int*)(eMv + (size_t)N_NODES * MAXE);
    float* zbuf = out + (size_t)N_NODES * N_NODES;  // z fp32 in d_out tail

    // precompute
    f2bf_k<<<2048, 256, 0, stream>>>(x, xb, 524288);
    transpose_bf16<<<dim3(16, 8, 4), dim3(32, 8), 0, stream>>>(W0, wt0, F_IN0, O_DIM);
    transpose_bf16<<<dim3(32, 8, 4), dim3(32, 8), 0, stream>>>(W1, wt1, HO, O_DIM);
    edges_k<<<N_NODES, 256, 0, stream>>>(adj, Mm, ecnt, eidx, eMv);

    // layer 0
    mfma_nt<<<dim3(32, 2, 4), 256, 0, stream>>>((const bf16_t*)xb, (const bf16_t*)wt0, hb,
                                                F_IN0, HO,
                                                (unsigned long long)O_DIM * F_IN0,
                                                (unsigned long long)O_DIM);
    scores_k<<<N_NODES, 256, 0, stream>>>(hb, as0, an0, s_self4, s_neigh4);
    attn_k<<<N_NODES, 256, 0, stream>>>(hb, ecnt, eidx, eMv, s_self4, s_neigh4, hin1b, nullptr, 0);

    // layer 1
    mfma_nt<<<dim3(32, 2, 4), 256, 0, stream>>>((const bf16_t*)hin1b, (const bf16_t*)wt1, hb,
                                                HO, HO,
                                                (unsigned long long)O_DIM * HO,
                                                (unsigned long long)O_DIM);
    scores_k<<<N_NODES, 256, 0, stream>>>(hb, as1, an1, s_self4, s_neigh4);
    attn_k<<<N_NODES, 256, 0, stream>>>(hb, ecnt, eidx, eMv, s_self4, s_neigh4, nullptr, zbuf, 1);

    // normalize + decode (direct-fragment MFMA, no LDS)
    norm_k<<<N_NODES, 256, 0, stream>>>(zbuf, zb);
    decode_k<<<dim3(32, 32), 256, 0, stream>>>((const bf16_t*)zb, out);
}

// Round 5
// 337.475 us; speedup vs baseline: 1.0838x; 1.0838x over previous
//
#include <hip/hip_runtime.h>
#include <hip/hip_bf16.h>
#include <math.h>

#define N_NODES 4096
#define F_IN0   512
#define HEADS   4
#define O_DIM   256
#define HO      1024   // HEADS*O_DIM
#define LRELU_A 0.2f
#define MAXE    192
#define LOG2E   1.44269504088896f

typedef __bf16 bf16_t;
typedef bf16_t bf16x8 __attribute__((ext_vector_type(8)));
typedef float f32x4 __attribute__((ext_vector_type(4)));
typedef unsigned short u16x8 __attribute__((ext_vector_type(8)));

__device__ __forceinline__ unsigned short f2b(float f) {
    __hip_bfloat16 t = __float2bfloat16(f);
    return __builtin_bit_cast(unsigned short, t);
}
__device__ __forceinline__ float b2f(unsigned short u) {
    unsigned int v = ((unsigned int)u) << 16;
    return __builtin_bit_cast(float, v);
}
__device__ __forceinline__ float fexp(float x) {          // e^x, hw exp2
    return __builtin_amdgcn_exp2f(x * LOG2E);
}
__device__ __forceinline__ float fsigmoid(float x) {      // 1/(1+e^-x)
    return __builtin_amdgcn_rcpf(1.f + __builtin_amdgcn_exp2f(-x * LOG2E));
}

#define GLOAD_LDS(g, l) \
    __builtin_amdgcn_global_load_lds((const __attribute__((address_space(1))) unsigned int*)(g), \
                                     (__attribute__((address_space(3))) unsigned int*)(l), 16, 0, 0)

// ---------------- fused preprocessing: f2bf(x) | transpose W0 | transpose W1 | edges
__device__ __forceinline__ void transpose_tile(const float* __restrict__ W,
                                               unsigned short* __restrict__ Wt,
                                               int K, int O, int kt, int ot, int h,
                                               float (*t)[33], int tid) {
    const float* Wh = W + (size_t)h * K * O;
    unsigned short* Wth = Wt + (size_t)h * K * O;
    const int k0 = kt * 32, o0 = ot * 32;
    const int tx = tid & 31, ty = tid >> 5;   // 32 x 8
    for (int r = ty; r < 32; r += 8) t[r][tx] = Wh[(size_t)(k0 + r) * O + o0 + tx];
    __syncthreads();
    for (int r = ty; r < 32; r += 8)
        Wth[(size_t)(o0 + r) * K + k0 + tx] = f2b(t[tx][r]);
}

__global__ __launch_bounds__(256) void prep_k(const float* __restrict__ x,
                                              const float* __restrict__ W0,
                                              const float* __restrict__ W1,
                                              const float* __restrict__ adj,
                                              const float* __restrict__ Mm,
                                              unsigned short* __restrict__ xb,
                                              unsigned short* __restrict__ wt0,
                                              unsigned short* __restrict__ wt1,
                                              int* __restrict__ ecnt,
                                              int* __restrict__ eidx,
                                              float* __restrict__ eMv) {
    __shared__ float t[32][33];
    __shared__ int cnt;
    const int b = blockIdx.x;
    const int tid = threadIdx.x;
    if (b < 2048) {                       // x -> bf16 (524288 float4 groups)
        int i = b * 256 + tid;
        float4 v = ((const float4*)x)[i];
        ushort4 o;
        o.x = f2b(v.x); o.y = f2b(v.y); o.z = f2b(v.z); o.w = f2b(v.w);
        ((ushort4*)xb)[i] = o;
    } else if (b < 2560) {                // W0 transpose: 16 kt x 8 ot x 4 h
        int b2 = b - 2048;
        transpose_tile(W0, wt0, F_IN0, O_DIM, (b2 & 15), ((b2 >> 4) & 7), b2 >> 7, t, tid);
    } else if (b < 3584) {                // W1 transpose: 32 kt x 8 ot x 4 h
        int b2 = b - 2560;
        transpose_tile(W1, wt1, HO, O_DIM, (b2 & 31), ((b2 >> 5) & 7), b2 >> 8, t, tid);
    } else {                              // edge list for row n
        const int n = b - 3584;
        if (tid == 0) cnt = 0;
        __syncthreads();
        const float* adjr = adj + (size_t)n * N_NODES;
        const float* Mr   = Mm  + (size_t)n * N_NODES;
        for (int m0 = tid * 4; m0 < N_NODES; m0 += 1024) {
            const float4 a4 = *(const float4*)&adjr[m0];
            const float av[4] = {a4.x, a4.y, a4.z, a4.w};
#pragma unroll
            for (int q = 0; q < 4; ++q) {
                if (av[q] > 0.f) {
                    int m = m0 + q;
                    int k = atomicAdd(&cnt, 1);
                    eidx[(size_t)n * MAXE + k] = m;
                    eMv[(size_t)n * MAXE + k]  = Mr[m];
                }
            }
        }
        __syncthreads();
        if (tid == 0) ecnt[n] = cnt;
    }
}

// ---------------- MFMA NT GEMM (LDS-staged; the two layer GEMMs)
__global__ __launch_bounds__(256) void mfma_nt(const bf16_t* __restrict__ A,
                                               const bf16_t* __restrict__ B,
                                               unsigned short* __restrict__ Cv,
                                               int K, int ldc,
                                               unsigned long long bStride,
                                               unsigned long long cStride) {
    B += blockIdx.z * bStride;
    const size_t zoff = (size_t)blockIdx.z * cStride;
    __shared__ bf16_t sA[128 * 32];
    __shared__ bf16_t sB[128 * 32];
    const int tid  = threadIdx.x;
    const int lane = tid & 63;
    const int wave = tid >> 6;
    const int wr = (wave >> 1) * 64;
    const int wc = (wave & 1) * 64;
    const int rowBase = blockIdx.x * 128;
    const int colBase = blockIdx.y * 128;
    const int l15  = lane & 15;
    const int quad = lane >> 4;

    const int sm = tid & 127;
    const int sc = tid >> 7;
    const bf16_t* aRow = A + (size_t)(rowBase + sm) * K + sc * 8;
    const bf16_t* bRow = B + (size_t)(colBase + sm) * K + sc * 8;
    bf16_t* sA0 = &sA[(tid & ~63) * 8];
    bf16_t* sA1 = &sA[(256 + (tid & ~63)) * 8];
    bf16_t* sB0 = &sB[(tid & ~63) * 8];
    bf16_t* sB1 = &sB[(256 + (tid & ~63)) * 8];

    f32x4 acc[4][4] = {};

    for (int k0 = 0; k0 < K; k0 += 32) {
        GLOAD_LDS(aRow + k0,      sA0);
        GLOAD_LDS(aRow + k0 + 16, sA1);
        GLOAD_LDS(bRow + k0,      sB0);
        GLOAD_LDS(bRow + k0 + 16, sB1);
        __syncthreads();
        bf16x8 af[4], bfr[4];
#pragma unroll
        for (int i = 0; i < 4; ++i) {
            af[i]  = *(bf16x8*)&sA[(quad * 128 + wr + i * 16 + l15) * 8];
            bfr[i] = *(bf16x8*)&sB[(quad * 128 + wc + i * 16 + l15) * 8];
        }
#pragma unroll
        for (int i = 0; i < 4; ++i)
#pragma unroll
            for (int j = 0; j < 4; ++j)
                acc[i][j] = __builtin_amdgcn_mfma_f32_16x16x32_bf16(af[i], bfr[j], acc[i][j], 0, 0, 0);
        __syncthreads();
    }

    const int orow = rowBase + wr + quad * 4;
    const int ocol = colBase + wc + l15;
#pragma unroll
    for (int i = 0; i < 4; ++i)
#pragma unroll
        for (int j = 0; j < 4; ++j)
#pragma unroll
            for (int r = 0; r < 4; ++r)
                Cv[zoff + (size_t)(orow + i * 16 + r) * ldc + ocol + j * 16] = f2b(acc[i][j][r]);
}

// ---------------- decode: out = sigmoid(Z Z^T), direct global fragments, fast sigmoid
__global__ __launch_bounds__(256) void decode_k(const bf16_t* __restrict__ Z,
                                                float* __restrict__ out) {
    const int tid  = threadIdx.x;
    const int lane = tid & 63;
    const int wave = tid >> 6;
    const int rowBase = blockIdx.x * 128 + (wave >> 1) * 64;
    const int colBase = blockIdx.y * 128 + (wave & 1) * 64;
    const int l15  = lane & 15;
    const int quad = lane >> 4;
    const bf16_t* aBase = Z + (size_t)(rowBase + l15) * O_DIM + quad * 8;
    const bf16_t* bBase = Z + (size_t)(colBase + l15) * O_DIM + quad * 8;

    f32x4 acc[4][4] = {};
#pragma unroll
    for (int kc = 0; kc < 8; ++kc) {
        bf16x8 a[4], b[4];
#pragma unroll
        for (int i = 0; i < 4; ++i) {
            a[i] = *(const bf16x8*)(aBase + (size_t)i * 16 * O_DIM + kc * 32);
            b[i] = *(const bf16x8*)(bBase + (size_t)i * 16 * O_DIM + kc * 32);
        }
#pragma unroll
        for (int i = 0; i < 4; ++i)
#pragma unroll
            for (int j = 0; j < 4; ++j)
                acc[i][j] = __builtin_amdgcn_mfma_f32_16x16x32_bf16(a[i], b[j], acc[i][j], 0, 0, 0);
    }

    const int orow = rowBase + quad * 4;
    const int ocol = colBase + l15;
#pragma unroll
    for (int i = 0; i < 4; ++i)
#pragma unroll
        for (int j = 0; j < 4; ++j)
#pragma unroll
            for (int r = 0; r < 4; ++r)
                out[(size_t)(orow + i * 16 + r) * N_NODES + ocol + j * 16] =
                    fsigmoid(acc[i][j][r]);
}

// ---------------- scores from bf16 h[n][h*256+o]
__global__ __launch_bounds__(256) void scores_k(const unsigned short* __restrict__ hb,
                                                const float* __restrict__ a_s,
                                                const float* __restrict__ a_n,
                                                float* __restrict__ s_self4,
                                                float* __restrict__ s_neigh4) {
    const int n = blockIdx.x;
    const int head = threadIdx.x >> 6;
    const int lane = threadIdx.x & 63;
    const ushort4 hv = *(const ushort4*)&hb[(size_t)n * HO + head * O_DIM + lane * 4];
    const float4 av = *(const float4*)&a_s[head * O_DIM + lane * 4];
    const float4 nv = *(const float4*)&a_n[head * O_DIM + lane * 4];
    float h0 = b2f(hv.x), h1 = b2f(hv.y), h2 = b2f(hv.z), h3 = b2f(hv.w);
    float ps = h0 * av.x + h1 * av.y + h2 * av.z + h3 * av.w;
    float pn = h0 * nv.x + h1 * nv.y + h2 * nv.z + h3 * nv.w;
    for (int off = 32; off; off >>= 1) {
        ps += __shfl_down(ps, off, 64);
        pn += __shfl_down(pn, off, 64);
    }
    if (lane == 0) {
        s_self4[n * HEADS + head]  = ps;
        s_neigh4[n * HEADS + head] = pn;
    }
}

// ---------------- sparse attention: parallel softmax + 2-way edge-parallel gather
__global__ __launch_bounds__(256) void attn_k(const unsigned short* __restrict__ hb,
                                              const int* __restrict__ ecnt,
                                              const int* __restrict__ eidx,
                                              const float* __restrict__ eMv,
                                              const float* __restrict__ s_self4,
                                              const float* __restrict__ s_neigh4,
                                              unsigned short* __restrict__ out0,
                                              float* __restrict__ out1, int layer) {
    const int n = blockIdx.x;
    const int tid = threadIdx.x;
    __shared__ int midx[MAXE];
    __shared__ float ev[MAXE][HEADS];
    __shared__ float red2[2][HO];
    const int c = ecnt[n];

    // phase 1: per-edge scores (leaky relu)
    if (tid < c) {
        const int m = eidx[(size_t)n * MAXE + tid];
        const float Mv = eMv[(size_t)n * MAXE + tid];
        midx[tid] = m;
        const float4 ss = *(const float4*)&s_self4[n * HEADS];
        const float4 sn = *(const float4*)&s_neigh4[m * HEADS];
        float e0 = (ss.x + sn.x) * Mv, e1 = (ss.y + sn.y) * Mv;
        float e2 = (ss.z + sn.z) * Mv, e3 = (ss.w + sn.w) * Mv;
        ev[tid][0] = e0 > 0.f ? e0 : LRELU_A * e0;
        ev[tid][1] = e1 > 0.f ? e1 : LRELU_A * e1;
        ev[tid][2] = e2 > 0.f ? e2 : LRELU_A * e2;
        ev[tid][3] = e3 > 0.f ? e3 : LRELU_A * e3;
    }
    __syncthreads();

    // phase 2: wave w = softmax over head w (shuffle butterfly)
    {
        const int w = tid >> 6, lane = tid & 63;
        float mx = -1e30f;
        for (int k = lane; k < c; k += 64) mx = fmaxf(mx, ev[k][w]);
        for (int off = 32; off; off >>= 1) mx = fmaxf(mx, __shfl_xor(mx, off, 64));
        float s = 0.f;
        for (int k = lane; k < c; k += 64) {
            float p = fexp(ev[k][w] - mx);
            ev[k][w] = p;
            s += p;
        }
        for (int off = 32; off; off >>= 1) s += __shfl_xor(s, off, 64);
        float inv = __builtin_amdgcn_rcpf(s);
        for (int k = lane; k < c; k += 64) ev[k][w] *= inv;
    }
    __syncthreads();

    // phase 3: gather-aggregate; halves process even/odd edges, 16B loads
    const int half = tid >> 7;
    const int t    = tid & 127;
    const int hh   = t >> 5;          // head of this thread's o-range
    float acc[8] = {};
#pragma unroll 2
    for (int k = half; k < c; k += 2) {
        const int m = midx[k];
        const float w = ev[k][hh];
        const u16x8 hv = *(const u16x8*)&hb[(size_t)m * HO + t * 8];
#pragma unroll
        for (int j = 0; j < 8; ++j) acc[j] += w * b2f(hv[j]);
    }
#pragma unroll
    for (int j = 0; j < 8; ++j) red2[half][t * 8 + j] = acc[j];
    __syncthreads();

    if (layer == 0) {
        const int o = tid * 4;
        ushort4 ov;
        float v0 = red2[0][o + 0] + red2[1][o + 0];
        float v1 = red2[0][o + 1] + red2[1][o + 1];
        float v2 = red2[0][o + 2] + red2[1][o + 2];
        float v3 = red2[0][o + 3] + red2[1][o + 3];
        ov.x = f2b(v0 > 0.f ? v0 : fexp(v0) - 1.f);
        ov.y = f2b(v1 > 0.f ? v1 : fexp(v1) - 1.f);
        ov.z = f2b(v2 > 0.f ? v2 : fexp(v2) - 1.f);
        ov.w = f2b(v3 > 0.f ? v3 : fexp(v3) - 1.f);
        *(ushort4*)&out0[(size_t)n * HO + o] = ov;
    } else {
        const int o = tid;
        float v = 0.f;
#pragma unroll
        for (int h = 0; h < HEADS; ++h)
            v += red2[0][h * O_DIM + o] + red2[1][h * O_DIM + o];
        out1[(size_t)n * O_DIM + o] = 0.25f * v;
    }
}

// ---------------- row L2 normalize + bf16 copy
__global__ __launch_bounds__(256) void norm_k(float* __restrict__ z,
                                              unsigned short* __restrict__ zb) {
    const int n = blockIdx.x;
    const int tid = threadIdx.x;
    float v = z[(size_t)n * O_DIM + tid];
    float p = v * v;
    for (int off = 32; off; off >>= 1) p += __shfl_down(p, off, 64);
    __shared__ float wsum[4];
    if ((tid & 63) == 0) wsum[tid >> 6] = p;
    __syncthreads();
    float ssq = wsum[0] + wsum[1] + wsum[2] + wsum[3];
    float denom = fmaxf(sqrtf(ssq), 1e-12f);
    float zn = v / denom;
    z[(size_t)n * O_DIM + tid] = zn;
    zb[(size_t)n * O_DIM + tid] = f2b(zn);
}

extern "C" void kernel_launch(void* const* d_in, const int* in_sizes, int n_in,
                              void* d_out, int out_size, void* d_ws, size_t ws_size,
                              hipStream_t stream) {
    const float* x   = (const float*)d_in[0];
    const float* adj = (const float*)d_in[1];
    const float* Mm  = (const float*)d_in[2];
    const float* W0  = (const float*)d_in[3];
    const float* as0 = (const float*)d_in[4];
    const float* an0 = (const float*)d_in[5];
    const float* W1  = (const float*)d_in[6];
    const float* as1 = (const float*)d_in[7];
    const float* an1 = (const float*)d_in[8];
    float* out = (float*)d_out;

    unsigned short* hb    = (unsigned short*)d_ws;        // [N][HO] bf16, 8 MB
    unsigned short* hin1b = hb + (size_t)N_NODES * HO;    // [N][HO] bf16, 8 MB
    unsigned short* xb    = hin1b + (size_t)N_NODES * HO; // [N][F] bf16, 4 MB
    unsigned short* wt0   = xb + (size_t)N_NODES * F_IN0; // 1 MB
    unsigned short* wt1   = wt0 + HEADS * O_DIM * F_IN0;  // 2 MB
    unsigned short* zb    = wt1 + HEADS * O_DIM * HO;     // [N][O] bf16, 2 MB
    float* s_self4  = (float*)(zb + (size_t)N_NODES * O_DIM);
    float* s_neigh4 = s_self4 + N_NODES * HEADS;
    int*   eidx = (int*)(s_neigh4 + N_NODES * HEADS);
    float* eMv  = (float*)(eidx + (size_t)N_NODES * MAXE);
    int*   ecnt = (int*)(eMv + (size_t)N_NODES * MAXE);
    float* zbuf = out + (size_t)N_NODES * N_NODES;  // z fp32 in d_out tail

    // fused preprocessing: f2bf | W0^T | W1^T | edge list
    prep_k<<<7680, 256, 0, stream>>>(x, W0, W1, adj, Mm, xb, wt0, wt1, ecnt, eidx, eMv);

    // layer 0
    mfma_nt<<<dim3(32, 2, 4), 256, 0, stream>>>((const bf16_t*)xb, (const bf16_t*)wt0, hb,
                                                F_IN0, HO,
                                                (unsigned long long)O_DIM * F_IN0,
                                                (unsigned long long)O_DIM);
    scores_k<<<N_NODES, 256, 0, stream>>>(hb, as0, an0, s_self4, s_neigh4);
    attn_k<<<N_NODES, 256, 0, stream>>>(hb, ecnt, eidx, eMv, s_self4, s_neigh4, hin1b, nullptr, 0);

    // layer 1
    mfma_nt<<<dim3(32, 2, 4), 256, 0, stream>>>((const bf16_t*)hin1b, (const bf16_t*)wt1, hb,
                                                HO, HO,
                                                (unsigned long long)O_DIM * HO,
                                                (unsigned long long)O_DIM);
    scores_k<<<N_NODES, 256, 0, stream>>>(hb, as1, an1, s_self4, s_neigh4);
    attn_k<<<N_NODES, 256, 0, stream>>>(hb, ecnt, eidx, eMv, s_self4, s_neigh4, nullptr, zbuf, 1);

    // normalize + decode
    norm_k<<<N_NODES, 256, 0, stream>>>(zbuf, zb);
    decode_k<<<dim3(32, 32), 256, 0, stream>>>((const bf16_t*)zb, out);
}